// Round 7
// baseline (427.146 us; speedup 1.0000x reference)
//
#include <hip/hip_runtime.h>
#include <hip/hip_bf16.h>

using bf16 = __hip_bfloat16;

typedef __attribute__((ext_vector_type(8))) short short8;   // 8 bf16 = 16B
typedef __attribute__((ext_vector_type(4))) float f32x4;    // 16B

#define MFMA_BF16(a, b, c) __builtin_amdgcn_mfma_f32_16x16x32_bf16((a), (b), (c), 0, 0, 0)

// async global->LDS, 16B per lane; LDS dest = wave-uniform base + lane*16
__device__ __forceinline__ void lds_load16(const void* g, void* l) {
    __builtin_amdgcn_global_load_lds(
        (const __attribute__((address_space(1))) void*)g,
        (__attribute__((address_space(3))) void*)l, 16, 0, 0);
}

// counted vmem wait (T4): wait until <= N vmem ops outstanding (oldest retire first)
template <int N>
__device__ __forceinline__ void waitvm() {
    asm volatile("s_waitcnt vmcnt(%0)" ::"n"(N) : "memory");
}
__device__ __forceinline__ void lgkm0_fence() {
    asm volatile("s_waitcnt lgkmcnt(0)" ::: "memory");
}

// XCD-aware block swizzle: flat%8 ~ XCD id. Requires gridDim.y % 8 == 0.
__device__ __forceinline__ void swiz_xcd(int& bx, int& by) {
    const int NX = gridDim.x, NY = gridDim.y;
    const int flat = blockIdx.y * NX + blockIdx.x;
    const int cid = flat & 7, slot = flat >> 3;
    by = cid * (NY >> 3) + slot / NX;
    bx = slot % NX;
}

// ---------------------------------------------------------------------------
// Bank-conflict-free staging (rule 21: LDS linear dest, XOR-permuted SOURCE,
// same XOR on the read side). NW = waves participating.
// ---------------------------------------------------------------------------
template <int ROWS, int NW>
__device__ __forceinline__ void stage_bf16(const bf16* src, int ld, bf16* tile,
                                           int wave, int lane) {
    const int r = lane >> 2;                          // 16 rows / wave-issue
    const int c = ((lane & 3) ^ ((r >> 1) & 3)) * 8;  // swizzled source chunk
#pragma unroll
    for (int p = 0; p < ROWS / (16 * NW); ++p) {
        const int row = p * (16 * NW) + wave * 16;    // base multiple of 16
        lds_load16(src + (size_t)(row + r) * ld + c, tile + row * 32);
    }
}
// fp32 tile, async (raw f32 into LDS; hi/lo conversion happens at read)
template <int ROWS, int NW>
__device__ __forceinline__ void stage_f32(const float* src, int ld, float* tile,
                                          int wave, int lane) {
    const int r = lane >> 3;                          // 8 rows / wave-issue
    const int c = ((lane & 7) ^ r) * 4;               // swizzled source chunk
#pragma unroll
    for (int p = 0; p < ROWS / (8 * NW); ++p) {
        const int row = p * (8 * NW) + wave * 8;      // base multiple of 8
        lds_load16(src + (size_t)(row + r) * ld + c, tile + row * 32);
    }
}

// swizzled reads ----------------------------------------------------------
__device__ __forceinline__ short8 rd_bf16(const bf16* tile, int row, int quad) {
    const int c = (quad ^ ((row >> 1) & 3)) * 8;
    return *(const short8*)(tile + row * 32 + c);
}
template <bool SPLIT>
__device__ __forceinline__ void rd_f32_hilo(const float* tile, int row, int quad,
                                            short8& h, short8& l) {
    const int f = row & 7;
    const f32x4 x0 = *(const f32x4*)(tile + row * 32 + ((2 * quad) ^ f) * 4);
    const f32x4 x1 = *(const f32x4*)(tile + row * 32 + ((2 * quad + 1) ^ f) * 4);
    float xs[8] = {x0[0], x0[1], x0[2], x0[3], x1[0], x1[1], x1[2], x1[3]};
#pragma unroll
    for (int j = 0; j < 8; ++j) {
        const bf16 hb = __float2bfloat16(xs[j]);
        h[j] = *(const short*)&hb;
        if constexpr (SPLIT) {
            const bf16 lb = __float2bfloat16(xs[j] - __bfloat162float(hb));
            l[j] = *(const short*)&lb;
        }
    }
}

// ---------------------------------------------------------------------------
// Weight transpose fp32 in[K][N] -> bf16 hi(/lo) out[N][K]
// ---------------------------------------------------------------------------
template <bool SPLIT>
__global__ void transpose_split(const float* __restrict__ in, bf16* __restrict__ outh,
                                bf16* __restrict__ outl, int K, int N) {
    __shared__ float t[32][33];
    const int n0 = blockIdx.x * 32, k0 = blockIdx.y * 32;
    const int tx = threadIdx.x, ty = threadIdx.y;  // (32, 8)
#pragma unroll
    for (int i = 0; i < 4; ++i)
        t[ty + i * 8][tx] = in[(size_t)(k0 + ty + i * 8) * N + n0 + tx];
    __syncthreads();
#pragma unroll
    for (int i = 0; i < 4; ++i) {
        const float x = t[tx][ty + i * 8];
        const bf16 hb = __float2bfloat16(x);
        const size_t idx = (size_t)(n0 + ty + i * 8) * K + k0 + tx;
        outh[idx] = hb;
        if constexpr (SPLIT) outl[idx] = __float2bfloat16(x - __bfloat162float(hb));
    }
}

// ---------------------------------------------------------------------------
// Unified 128x128x32 MFMA GEMM, C = A @ Bt^T (+bias). 512 thr = 8 waves
// (4 row-groups x 2 col-groups; per wave 32x64 out = acc[2][4]).
// TRIPLE-buffer barrier-light pipeline: buffer (t+2)%3 was last READ at step
// t-1; each wave's t-1 ds_reads complete before its t-1 MFMAs (compiler lgkm
// waits) and the sched_barrier(0) at loop end pins those MFMAs inside the
// iteration (rule 18: hipcc may otherwise sink register-only MFMAs past the
// next inline-asm wait/barrier). So all t-1 reads are consumed before any
// wave passes barrier(t), and staging t+2 after barrier(t) cannot race them.
// Per K-step: waitvm<S> (own tile-t loads retired; every wave does this
// BEFORE the barrier, so post-barrier tile t is globally resident; tile t+1
// stays IN FLIGHT, never drained) -> ONE s_barrier -> issue stage(t+2) ->
// ds_read frags [compiler emits fine-grained lgkmcnt(N) into the MFMA
// cluster] -> setprio(1) MFMA setprio(0) -> sched_barrier(0).
//  G_SPLIT3: A fp32 async, hi/lo conv in regs; B bf16 hi/lo; 3-MFMA. S=4.
//  G_VT    : A fp32 async, hi conv; B bf16; out bf16 transposed. S=3.
//  G_F32   : A bf16; B bf16; out fp32 + bias. S=2.
//  G_PV    : batched (z): A bf16; B bf16; out bf16, no bias. S=2.
// ---------------------------------------------------------------------------
enum { G_SPLIT3 = 0, G_VT = 1, G_F32 = 2, G_PV = 3 };

template <int MODE>
__global__ __launch_bounds__(512, 4) void gemm2(
    const void* __restrict__ Av, const bf16* __restrict__ Bth,
    const bf16* __restrict__ Btl, const float* __restrict__ bias,
    void* __restrict__ out0, void* __restrict__ out1, int N, int K) {
    constexpr bool ASPLIT = (MODE == G_SPLIT3);
    constexpr bool ACONV = (MODE == G_SPLIT3 || MODE == G_VT);
    constexpr int SZ_A = ACONV ? 128 * 32 * 4 : 128 * 32 * 2;
    constexpr int SZ_B = 128 * 32 * 2;
    constexpr int STAGE = SZ_A + SZ_B + (ASPLIT ? SZ_B : 0);
    constexpr int TBUF = 3 * STAGE;
    constexpr int SMEM =
        (MODE == G_VT) ? (TBUF > 128 * 136 * 2 ? TBUF : 128 * 136 * 2) : TBUF;
    constexpr int SLOADS = ACONV ? (ASPLIT ? 4 : 3) : 2;  // global_load_lds / lane / stage
    __shared__ __align__(16) char smem[SMEM];
    bf16* Ts = (bf16*)smem;  // G_VT epilogue only (staging dead by then)

    const int tid = threadIdx.x, wave = tid >> 6, lane = tid & 63;
    const int quad = lane >> 4, l15 = lane & 15;
    const int wr = wave >> 1, wc = wave & 1;  // 4 row-groups x 2 col-groups

    int bx, by;
    if constexpr (MODE == G_PV) {
        bx = blockIdx.x;
        by = blockIdx.y;
    } else {
        swiz_xcd(bx, by);
    }
    const int m0 = by * 128, n0 = bx * 128;
    const int z = blockIdx.z;

    const float* Af = (const float*)Av;
    const bf16* Ab = (const bf16*)Av;
    const bf16* Bh = Bth;
    if constexpr (MODE == G_PV) {
        Ab += (size_t)z * 256 * 256;   // beta batch
        Bh += (size_t)z * 1024 * 256;  // vT batch
    }

    auto do_stage = [&](int k0, char* base) {
        if constexpr (ACONV)
            stage_f32<128, 8>(Af + (size_t)m0 * K + k0, K, (float*)base, wave, lane);
        else
            stage_bf16<128, 8>(Ab + (size_t)m0 * K + k0, K, (bf16*)base, wave, lane);
        stage_bf16<128, 8>(Bh + (size_t)n0 * K + k0, K, (bf16*)(base + SZ_A), wave, lane);
        if constexpr (ASPLIT)
            stage_bf16<128, 8>(Btl + (size_t)n0 * K + k0, K, (bf16*)(base + SZ_A + SZ_B),
                               wave, lane);
    };

    f32x4 acc[2][4] = {};
    const int nt = K / 32;
    do_stage(0, smem);
    do_stage(32, smem + STAGE);  // 2 tiles in flight
    int cur = 0;
    for (int t = 0; t < nt; ++t) {
        if (t + 1 < nt)
            waitvm<SLOADS>();  // own tile-t loads retired; t+1 stays in flight
        else
            waitvm<0>();
        __builtin_amdgcn_s_barrier();  // all waves: tile t resident, t-1 reads consumed

        if (t + 2 < nt) {  // stage into buffer last read at t-1 (safe post-barrier)
            int nb = cur + 2;
            if (nb >= 3) nb -= 3;
            do_stage((t + 2) * 32, smem + nb * STAGE);
        }

        char* base = smem + cur * STAGE;
        const float* AsF = (const float*)base;
        const bf16* AsH = (const bf16*)base;
        const bf16* BsH = (const bf16*)(base + SZ_A);
        const bf16* BsL = (const bf16*)(base + SZ_A + SZ_B);

        short8 ah[2], al[2], bh[4], bl[4];
#pragma unroll
        for (int tt = 0; tt < 2; ++tt) {
            const int ra = wr * 32 + tt * 16 + l15;
            if constexpr (ACONV)
                rd_f32_hilo<ASPLIT>(AsF, ra, quad, ah[tt], al[tt]);
            else
                ah[tt] = rd_bf16(AsH, ra, quad);
        }
#pragma unroll
        for (int tt = 0; tt < 4; ++tt) {
            const int rb = wc * 64 + tt * 16 + l15;
            bh[tt] = rd_bf16(BsH, rb, quad);
            if constexpr (ASPLIT) bl[tt] = rd_bf16(BsL, rb, quad);
        }
        __builtin_amdgcn_s_setprio(1);
        if constexpr (ASPLIT) {
#pragma unroll
            for (int ti = 0; ti < 2; ++ti)
#pragma unroll
                for (int tj = 0; tj < 4; ++tj) {
                    acc[ti][tj] = MFMA_BF16(al[ti], bh[tj], acc[ti][tj]);
                    acc[ti][tj] = MFMA_BF16(ah[ti], bl[tj], acc[ti][tj]);
                    acc[ti][tj] = MFMA_BF16(ah[ti], bh[tj], acc[ti][tj]);
                }
        } else {
#pragma unroll
            for (int ti = 0; ti < 2; ++ti)
#pragma unroll
                for (int tj = 0; tj < 4; ++tj)
                    acc[ti][tj] = MFMA_BF16(ah[ti], bh[tj], acc[ti][tj]);
        }
        __builtin_amdgcn_s_setprio(0);
        __builtin_amdgcn_sched_barrier(0);  // rule 18: pin MFMAs (+lgkm waits) here
        ++cur;
        if (cur == 3) cur = 0;
    }

    float bv4[4] = {0.f, 0.f, 0.f, 0.f};
    if constexpr (MODE != G_PV) {
#pragma unroll
        for (int tj = 0; tj < 4; ++tj) bv4[tj] = bias[n0 + wc * 64 + tj * 16 + l15];
    }

    if constexpr (MODE == G_VT) {
        __syncthreads();  // all waves done with staging buffers before Ts overwrite
#pragma unroll
        for (int ti = 0; ti < 2; ++ti)
#pragma unroll
            for (int tj = 0; tj < 4; ++tj)
#pragma unroll
                for (int i = 0; i < 4; ++i) {
                    const int ml = wr * 32 + ti * 16 + quad * 4 + i;
                    const int nl = wc * 64 + tj * 16 + l15;
                    Ts[nl * 136 + ml] = __float2bfloat16(acc[ti][tj][i] + bv4[tj]);
                }
        __syncthreads();
        const int bIdx = m0 >> 8, tok0 = m0 & 255;
        const int nl = tid >> 2, qtr = tid & 3;  // 512 thr: 128 n x 4 token-qtrs
        bf16* dst =
            (bf16*)out0 + ((size_t)bIdx * N + n0 + nl) * 256 + tok0 + qtr * 32;
        const bf16* src = &Ts[nl * 136 + qtr * 32];
#pragma unroll
        for (int j = 0; j < 4; ++j)
            *(short8*)(dst + j * 8) = *(const short8*)(src + j * 8);
    } else {
#pragma unroll
        for (int ti = 0; ti < 2; ++ti)
#pragma unroll
            for (int tj = 0; tj < 4; ++tj)
#pragma unroll
                for (int i = 0; i < 4; ++i) {
                    const size_t row = m0 + wr * 32 + ti * 16 + quad * 4 + i;
                    const size_t col = n0 + wc * 64 + tj * 16 + l15;
                    const float v = acc[ti][tj][i] + bv4[tj];
                    if constexpr (MODE == G_F32) {
                        ((float*)out0)[row * N + col] = v;
                    } else if constexpr (MODE == G_PV) {
                        ((bf16*)out0)[((size_t)z * 256 + row) * N + col] =
                            __float2bfloat16(v);
                    } else {  // G_SPLIT3: hi/lo outputs
                        const bf16 hb = __float2bfloat16(v);
                        ((bf16*)out0)[row * N + col] = hb;
                        ((bf16*)out1)[row * N + col] =
                            __float2bfloat16(v - __bfloat162float(hb));
                    }
                }
    }
}

// ---------------------------------------------------------------------------
// s + softmax + mask: block = (32 q-rows, batch); 512 thr = 8 waves
// wave = (wr 0..1 row-tile, wq 0..3 col-quarter). k hi/lo double-buffered in
// LDS (swizzled, conflict-free), counted-vmcnt 2-buffer schedule (S=4).
// (unchanged to isolate the gemm2 pipeline lever)
// ---------------------------------------------------------------------------
__global__ __launch_bounds__(512) void attn_s(
    const bf16* __restrict__ qh, const bf16* __restrict__ ql,
    const bf16* __restrict__ kh, const bf16* __restrict__ kl,
    const float* __restrict__ masks, float* __restrict__ beta_out,
    bf16* __restrict__ betaB) {
    __shared__ bf16 kH[2][256 * 32], kL[2][256 * 32];
    __shared__ float redM[4][32], redS[4][32];
    int qt, b;
    swiz_xcd(qt, b);  // grid (8, 64): each XCD owns 8 batches; k fetched once
    const int tid = threadIdx.x, wave = tid >> 6, lane = tid & 63;
    const int quad = lane >> 4, l15 = lane & 15;
    const int wr = wave >> 2, wq = wave & 3;

    f32x4 acc[4] = {};
    const size_t qoff = ((size_t)(b * 256 + qt * 32 + wr * 16 + l15)) * 512;
    const size_t kbase = (size_t)(b * 256) * 512;

    stage_bf16<256, 8>(kh + kbase, 512, kH[0], wave, lane);
    stage_bf16<256, 8>(kl + kbase, 512, kL[0], wave, lane);
    stage_bf16<256, 8>(kh + kbase + 32, 512, kH[1], wave, lane);
    stage_bf16<256, 8>(kl + kbase + 32, 512, kL[1], wave, lane);
    int cur = 0;
    for (int t = 0; t < 16; ++t) {
        const int k0 = t * 32;
        if (t + 1 < 16)
            waitvm<4>();
        else
            waitvm<0>();
        __builtin_amdgcn_s_barrier();  // (A) tile t resident

        const short8 aH = *(const short8*)(qh + qoff + k0 + quad * 8);
        const short8 aL = *(const short8*)(ql + qoff + k0 + quad * 8);
        short8 bH[4], bL[4];
#pragma unroll
        for (int nt = 0; nt < 4; ++nt) {
            const int kr = wq * 64 + nt * 16 + l15;
            bH[nt] = rd_bf16(kH[cur], kr, quad);
            bL[nt] = rd_bf16(kL[cur], kr, quad);
        }
        lgkm0_fence();
        __builtin_amdgcn_s_barrier();  // (B) buf[cur] fully read
        if (t + 2 < 16) {
            stage_bf16<256, 8>(kh + kbase + (t + 2) * 32, 512, kH[cur], wave, lane);
            stage_bf16<256, 8>(kl + kbase + (t + 2) * 32, 512, kL[cur], wave, lane);
        }
#pragma unroll
        for (int nt = 0; nt < 4; ++nt) {
            acc[nt] = MFMA_BF16(aH, bH[nt], acc[nt]);
            acc[nt] = MFMA_BF16(aH, bL[nt], acc[nt]);
            acc[nt] = MFMA_BF16(aL, bH[nt], acc[nt]);
        }
        __builtin_amdgcn_sched_barrier(0);
        cur ^= 1;
    }

    // per-wave partial softmax over its 64 cols
    float pm[4], ps[4];
#pragma unroll
    for (int i = 0; i < 4; ++i) {
        float m = fmaxf(fmaxf(acc[0][i], acc[1][i]), fmaxf(acc[2][i], acc[3][i]));
#pragma unroll
        for (int s = 1; s < 16; s <<= 1) m = fmaxf(m, __shfl_xor(m, s));
        float sum = 0.f;
#pragma unroll
        for (int nt = 0; nt < 4; ++nt) sum += __expf(acc[nt][i] - m);
#pragma unroll
        for (int s = 1; s < 16; s <<= 1) sum += __shfl_xor(sum, s);
        pm[i] = m;
        ps[i] = sum;
    }
    if (l15 == 0) {
#pragma unroll
        for (int i = 0; i < 4; ++i) {
            redM[wq][wr * 16 + quad * 4 + i] = pm[i];
            redS[wq][wr * 16 + quad * 4 + i] = ps[i];
        }
    }
    __syncthreads();
    float gm[4], ginv[4];
#pragma unroll
    for (int i = 0; i < 4; ++i) {
        const int r = wr * 16 + quad * 4 + i;
        const float m = fmaxf(fmaxf(redM[0][r], redM[1][r]), fmaxf(redM[2][r], redM[3][r]));
        const float s = redS[0][r] * __expf(redM[0][r] - m) +
                        redS[1][r] * __expf(redM[1][r] - m) +
                        redS[2][r] * __expf(redM[2][r] - m) +
                        redS[3][r] * __expf(redM[3][r] - m);
        gm[i] = m;
        ginv[i] = 1.0f / s;
    }
#pragma unroll
    for (int nt = 0; nt < 4; ++nt) {
        const int col = wq * 64 + nt * 16 + l15;
        const float mv = masks[b * 256 + col];
#pragma unroll
        for (int i = 0; i < 4; ++i) {
            const int row = qt * 32 + wr * 16 + quad * 4 + i;
            const float bvv = __expf(acc[nt][i] - gm[i]) * ginv[i] * mv;
            const size_t idx = ((size_t)(b * 256 + row)) * 256 + col;
            beta_out[idx] = bvv;
            betaB[idx] = __float2bfloat16(bvv);
        }
    }
}

// ---------------------------------------------------------------------------
extern "C" void kernel_launch(void* const* d_in, const int* in_sizes, int n_in,
                              void* d_out, int out_size, void* d_ws, size_t ws_size,
                              hipStream_t stream) {
    const float* x1 = (const float*)d_in[0];
    const float* x2 = (const float*)d_in[1];
    const float* masks = (const float*)d_in[2];
    const float* Wq = (const float*)d_in[3];
    const float* bq = (const float*)d_in[4];
    const float* Wk = (const float*)d_in[5];
    const float* bk = (const float*)d_in[6];
    const float* Wv = (const float*)d_in[7];
    const float* bv = (const float*)d_in[8];
    const float* Wo = (const float*)d_in[9];
    const float* bo = (const float*)d_in[10];

    char* ws = (char*)d_ws;
    bf16* WqTh = (bf16*)(ws + 0);            // 512x1024
    bf16* WqTl = (bf16*)(ws + 1048576);
    bf16* WkTh = (bf16*)(ws + 2097152);      // 512x768
    bf16* WkTl = (bf16*)(ws + 2883584);
    bf16* WvTh = (bf16*)(ws + 3670016);      // 1024x768
    bf16* WoTh = (bf16*)(ws + 5242880);      // 1024x1024
    bf16* qh = (bf16*)(ws + 7340032);        // 16384x512
    bf16* ql = (bf16*)(ws + 24117248);
    bf16* kh = (bf16*)(ws + 40894464);
    bf16* kl = (bf16*)(ws + 57671680);
    bf16* vT = (bf16*)(ws + 74448896);       // [b][ch][tok] bf16
    bf16* betaB = (bf16*)(ws + 108003328);   // 16384x256
    bf16* o_mid = (bf16*)(ws + 7340032);     // overlays qh/ql (dead after attn_s)
    // total ws use: 116,391,936 bytes

    float* out_o = (float*)d_out;
    float* out_beta = out_o + (size_t)16384 * 1024;

    const dim3 tb(32, 8);
    transpose_split<true><<<dim3(16, 32), tb, 0, stream>>>(Wq, WqTh, WqTl, 1024, 512);
    transpose_split<true><<<dim3(16, 24), tb, 0, stream>>>(Wk, WkTh, WkTl, 768, 512);
    transpose_split<false><<<dim3(32, 24), tb, 0, stream>>>(Wv, WvTh, nullptr, 768, 1024);
    transpose_split<false><<<dim3(32, 32), tb, 0, stream>>>(Wo, WoTh, nullptr, 1024, 1024);

    // q = x1@Wq + bq -> hi/lo ; k = x2@Wk + bk -> hi/lo
    gemm2<G_SPLIT3><<<dim3(4, 128), 512, 0, stream>>>(x1, WqTh, WqTl, bq, qh, ql, 512, 1024);
    gemm2<G_SPLIT3><<<dim3(4, 128), 512, 0, stream>>>(x2, WkTh, WkTl, bk, kh, kl, 512, 768);
    // v = x2@Wv + bv -> vT[b][ch][tok]
    gemm2<G_VT><<<dim3(8, 128), 512, 0, stream>>>(x2, WvTh, nullptr, bv, vT, nullptr, 1024, 768);

    // s = q@k^T, softmax, mask -> beta (fp32 out + bf16 ws)
    attn_s<<<dim3(8, 64), 512, 0, stream>>>(qh, ql, kh, kl, masks, out_beta, betaB);

    // o_mid = beta @ v (batched)
    gemm2<G_PV><<<dim3(8, 2, 64), 512, 0, stream>>>(betaB, vT, nullptr, nullptr, o_mid,
                                                    nullptr, 1024, 256);
    // out = o_mid@Wo + bo (fp32)
    gemm2<G_F32><<<dim3(8, 128), 512, 0, stream>>>(o_mid, WoTh, nullptr, bo, out_o,
                                                   nullptr, 1024, 1024);
}

// Round 8
// 410.075 us; speedup vs baseline: 1.0416x; 1.0416x over previous
//
#include <hip/hip_runtime.h>
#include <hip/hip_bf16.h>

using bf16 = __hip_bfloat16;

typedef __attribute__((ext_vector_type(8))) short short8;   // 8 bf16 = 16B
typedef __attribute__((ext_vector_type(4))) float f32x4;    // 16B

#define MFMA_BF16(a, b, c) __builtin_amdgcn_mfma_f32_16x16x32_bf16((a), (b), (c), 0, 0, 0)

// async global->LDS, 16B per lane; LDS dest = wave-uniform base + lane*16
__device__ __forceinline__ void lds_load16(const void* g, void* l) {
    __builtin_amdgcn_global_load_lds(
        (const __attribute__((address_space(1))) void*)g,
        (__attribute__((address_space(3))) void*)l, 16, 0, 0);
}

// counted vmem wait (T4): wait until <= N vmem ops outstanding (oldest retire first)
template <int N>
__device__ __forceinline__ void waitvm() {
    asm volatile("s_waitcnt vmcnt(%0)" ::"n"(N) : "memory");
}
__device__ __forceinline__ void lgkm0_fence() {
    asm volatile("s_waitcnt lgkmcnt(0)" ::: "memory");
}

// XCD-aware block swizzle: flat%8 ~ XCD id. Requires gridDim.y % 8 == 0.
__device__ __forceinline__ void swiz_xcd(int& bx, int& by) {
    const int NX = gridDim.x, NY = gridDim.y;
    const int flat = blockIdx.y * NX + blockIdx.x;
    const int cid = flat & 7, slot = flat >> 3;
    by = cid * (NY >> 3) + slot / NX;
    bx = slot % NX;
}

// ---------------------------------------------------------------------------
// Bank-conflict-free staging (rule 21: LDS linear dest, XOR-permuted SOURCE,
// same XOR on the read side).
// ---------------------------------------------------------------------------
__device__ __forceinline__ void stage_bf16_128(const bf16* src, int ld, bf16* tile,
                                               int wave, int lane) {
    const int r = lane >> 2;                          // 16 rows / wave-issue
    const int c = ((lane & 3) ^ ((r >> 1) & 3)) * 8;  // swizzled source chunk
#pragma unroll
    for (int p = 0; p < 2; ++p) {
        const int row = p * 64 + wave * 16;           // base multiple of 16
        lds_load16(src + (size_t)(row + r) * ld + c, tile + row * 32);
    }
}
// 256x32 bf16 tile with 512-thr block (8 waves)
__device__ __forceinline__ void stage_bf16_256_w8(const bf16* src, int ld, bf16* tile,
                                                  int wave, int lane) {
    const int r = lane >> 2;
    const int c = ((lane & 3) ^ ((r >> 1) & 3)) * 8;
#pragma unroll
    for (int p = 0; p < 2; ++p) {
        const int row = p * 128 + wave * 16;
        lds_load16(src + (size_t)(row + r) * ld + c, tile + row * 32);
    }
}
// 128x32 fp32 tile, async (raw f32 into LDS; hi/lo conversion happens at read)
__device__ __forceinline__ void stage_f32_128(const float* src, int ld, float* tile,
                                              int wave, int lane) {
    const int r = lane >> 3;                          // 8 rows / wave-issue
    const int c = ((lane & 7) ^ r) * 4;               // swizzled source chunk
#pragma unroll
    for (int it = 0; it < 4; ++it) {
        const int row = it * 32 + wave * 8;           // base multiple of 8
        lds_load16(src + (size_t)(row + r) * ld + c, tile + row * 32);
    }
}

// swizzled reads ----------------------------------------------------------
__device__ __forceinline__ short8 rd_bf16(const bf16* tile, int row, int quad) {
    const int c = (quad ^ ((row >> 1) & 3)) * 8;
    return *(const short8*)(tile + row * 32 + c);
}
template <bool SPLIT>
__device__ __forceinline__ void rd_f32_hilo(const float* tile, int row, int quad,
                                            short8& h, short8& l) {
    const int f = row & 7;
    const f32x4 x0 = *(const f32x4*)(tile + row * 32 + ((2 * quad) ^ f) * 4);
    const f32x4 x1 = *(const f32x4*)(tile + row * 32 + ((2 * quad + 1) ^ f) * 4);
    float xs[8] = {x0[0], x0[1], x0[2], x0[3], x1[0], x1[1], x1[2], x1[3]};
#pragma unroll
    for (int j = 0; j < 8; ++j) {
        const bf16 hb = __float2bfloat16(xs[j]);
        h[j] = *(const short*)&hb;
        if constexpr (SPLIT) {
            const bf16 lb = __float2bfloat16(xs[j] - __bfloat162float(hb));
            l[j] = *(const short*)&lb;
        }
    }
}

// ---------------------------------------------------------------------------
// Weight transpose fp32 in[K][N] -> bf16 hi(/lo) out[N][K]
// ---------------------------------------------------------------------------
template <bool SPLIT>
__global__ void transpose_split(const float* __restrict__ in, bf16* __restrict__ outh,
                                bf16* __restrict__ outl, int K, int N) {
    __shared__ float t[32][33];
    const int n0 = blockIdx.x * 32, k0 = blockIdx.y * 32;
    const int tx = threadIdx.x, ty = threadIdx.y;  // (32, 8)
#pragma unroll
    for (int i = 0; i < 4; ++i)
        t[ty + i * 8][tx] = in[(size_t)(k0 + ty + i * 8) * N + n0 + tx];
    __syncthreads();
#pragma unroll
    for (int i = 0; i < 4; ++i) {
        const float x = t[tx][ty + i * 8];
        const bf16 hb = __float2bfloat16(x);
        const size_t idx = (size_t)(n0 + ty + i * 8) * K + k0 + tx;
        outh[idx] = hb;
        if constexpr (SPLIT) outl[idx] = __float2bfloat16(x - __bfloat162float(hb));
    }
}

// ---------------------------------------------------------------------------
// Unified 128x128x32 MFMA GEMM, C = A @ Bt^T (+bias). 256 thr = 4 waves,
// 4x4 16x16 tiles per wave (2x2 wave grid -> minimal 2x/2x LDS re-read amp).
// Per-mode best-measured K-loop schedule:
//  SPLIT3 (best @69.1us): 2-phase dbuf, stage(t+1) BEFORE compute(t), single
//    __syncthreads per step (R2 config).
//  VT/F32/PV (best-total config): counted-vmcnt 2-buffer: waitvm<S> (tile
//    t+1 stays in flight) -> barA -> ds_read -> lgkm0 -> barB -> stage(t+2)
//    -> MFMA (R4 config).
//  G_SPLIT3: A fp32 async, hi/lo conv in regs; B bf16 hi/lo; 3-MFMA.
//  G_VT    : A fp32 async, hi conv; B bf16; out bf16 transposed. S=6.
//  G_F32   : A bf16; B bf16; out fp32 + bias. S=4.
//  G_PV    : batched (z): A bf16; B bf16; out bf16, no bias. S=4.
// ---------------------------------------------------------------------------
enum { G_SPLIT3 = 0, G_VT = 1, G_F32 = 2, G_PV = 3 };

template <int MODE>
__global__ __launch_bounds__(256) void gemm2(
    const void* __restrict__ Av, const bf16* __restrict__ Bth,
    const bf16* __restrict__ Btl, const float* __restrict__ bias,
    void* __restrict__ out0, void* __restrict__ out1, int N, int K) {
    constexpr bool ASPLIT = (MODE == G_SPLIT3);
    constexpr bool ACONV = (MODE == G_SPLIT3 || MODE == G_VT);
    constexpr int SZ_A = ACONV ? 128 * 32 * 4 : 128 * 32 * 2;
    constexpr int SZ_B = 128 * 32 * 2;
    constexpr int STAGE = SZ_A + SZ_B + (ASPLIT ? SZ_B : 0);
    constexpr int DBUF = 2 * STAGE;
    constexpr int SMEM =
        (MODE == G_VT) ? (DBUF > 128 * 136 * 2 ? DBUF : 128 * 136 * 2) : DBUF;
    constexpr int SLOADS = ACONV ? (ASPLIT ? 8 : 6) : 4;  // global_load_lds / lane / stage
    __shared__ __align__(16) char smem[SMEM];
    bf16* Ts = (bf16*)smem;  // G_VT epilogue only (staging dead by then)

    const int tid = threadIdx.x, wave = tid >> 6, lane = tid & 63;
    const int quad = lane >> 4, l15 = lane & 15;
    const int wr = wave >> 1, wc = wave & 1;

    int bx, by;
    if constexpr (MODE == G_PV) {
        bx = blockIdx.x;
        by = blockIdx.y;
    } else {
        swiz_xcd(bx, by);
    }
    const int m0 = by * 128, n0 = bx * 128;
    const int z = blockIdx.z;

    const float* Af = (const float*)Av;
    const bf16* Ab = (const bf16*)Av;
    const bf16* Bh = Bth;
    if constexpr (MODE == G_PV) {
        Ab += (size_t)z * 256 * 256;   // beta batch
        Bh += (size_t)z * 1024 * 256;  // vT batch
    }

    auto do_stage = [&](int k0, char* base) {
        if constexpr (ACONV)
            stage_f32_128(Af + (size_t)m0 * K + k0, K, (float*)base, wave, lane);
        else
            stage_bf16_128(Ab + (size_t)m0 * K + k0, K, (bf16*)base, wave, lane);
        stage_bf16_128(Bh + (size_t)n0 * K + k0, K, (bf16*)(base + SZ_A), wave, lane);
        if constexpr (ASPLIT)
            stage_bf16_128(Btl + (size_t)n0 * K + k0, K, (bf16*)(base + SZ_A + SZ_B),
                           wave, lane);
    };

    f32x4 acc[4][4] = {};
    short8 ah[4], al[4], bh[4], bl[4];

    auto read_frags = [&](char* base) {
        const float* AsF = (const float*)base;
        const bf16* AsH = (const bf16*)base;
        const bf16* BsH = (const bf16*)(base + SZ_A);
        const bf16* BsL = (const bf16*)(base + SZ_A + SZ_B);
#pragma unroll
        for (int tt = 0; tt < 4; ++tt) {
            const int ra = wr * 64 + tt * 16 + l15;
            const int rb = wc * 64 + tt * 16 + l15;
            if constexpr (ACONV)
                rd_f32_hilo<ASPLIT>(AsF, ra, quad, ah[tt], al[tt]);
            else
                ah[tt] = rd_bf16(AsH, ra, quad);
            bh[tt] = rd_bf16(BsH, rb, quad);
            if constexpr (ASPLIT) bl[tt] = rd_bf16(BsL, rb, quad);
        }
    };
    auto do_mfma = [&]() {
        if constexpr (ASPLIT) {
#pragma unroll
            for (int ti = 0; ti < 4; ++ti)
#pragma unroll
                for (int tj = 0; tj < 4; ++tj) {
                    acc[ti][tj] = MFMA_BF16(al[ti], bh[tj], acc[ti][tj]);
                    acc[ti][tj] = MFMA_BF16(ah[ti], bl[tj], acc[ti][tj]);
                    acc[ti][tj] = MFMA_BF16(ah[ti], bh[tj], acc[ti][tj]);
                }
        } else {
#pragma unroll
            for (int ti = 0; ti < 4; ++ti)
#pragma unroll
                for (int tj = 0; tj < 4; ++tj)
                    acc[ti][tj] = MFMA_BF16(ah[ti], bh[tj], acc[ti][tj]);
        }
    };

    const int nt = K / 32;
    int cur = 0;
    if constexpr (ASPLIT) {
        // R2-style 2-phase: stage(t+1) -> compute(t) -> one __syncthreads.
        do_stage(0, smem);
        __syncthreads();
        for (int t = 0; t < nt; ++t) {
            char* base = smem + cur * STAGE;
            if (t + 1 < nt) do_stage((t + 1) * 32, smem + (cur ^ 1) * STAGE);
            read_frags(base);
            do_mfma();
            __syncthreads();
            cur ^= 1;
        }
    } else {
        // R4-style counted-vmcnt 2-buffer (tile t+1 never drained).
        do_stage(0, smem);
        do_stage(32, smem + STAGE);
        for (int t = 0; t < nt; ++t) {
            if (t + 1 < nt)
                waitvm<SLOADS>();
            else
                waitvm<0>();
            __builtin_amdgcn_s_barrier();  // (A) tile t resident on all waves
            char* base = smem + cur * STAGE;
            read_frags(base);
            lgkm0_fence();
            __builtin_amdgcn_s_barrier();  // (B) buf[cur] fully read by all
            if (t + 2 < nt) do_stage((t + 2) * 32, base);
            do_mfma();
            cur ^= 1;
        }
    }

    float bv4[4] = {0.f, 0.f, 0.f, 0.f};
    if constexpr (MODE != G_PV) {
#pragma unroll
        for (int tj = 0; tj < 4; ++tj) bv4[tj] = bias[n0 + wc * 64 + tj * 16 + l15];
    }

    if constexpr (MODE == G_VT) {
#pragma unroll
        for (int ti = 0; ti < 4; ++ti)
#pragma unroll
            for (int tj = 0; tj < 4; ++tj)
#pragma unroll
                for (int i = 0; i < 4; ++i) {
                    const int ml = wr * 64 + ti * 16 + quad * 4 + i;
                    const int nl = wc * 64 + tj * 16 + l15;
                    Ts[nl * 136 + ml] = __float2bfloat16(acc[ti][tj][i] + bv4[tj]);
                }
        __syncthreads();
        const int bIdx = m0 >> 8, tok0 = m0 & 255;
        const int nl = tid >> 1, half = tid & 1;
        bf16* dst = (bf16*)out0 + ((size_t)bIdx * N + n0 + nl) * 256 + tok0 + half * 64;
        const bf16* src = &Ts[nl * 136 + half * 64];
#pragma unroll
        for (int j = 0; j < 8; ++j)
            *(short8*)(dst + j * 8) = *(const short8*)(src + j * 8);
    } else {
#pragma unroll
        for (int ti = 0; ti < 4; ++ti)
#pragma unroll
            for (int tj = 0; tj < 4; ++tj)
#pragma unroll
                for (int i = 0; i < 4; ++i) {
                    const size_t row = m0 + wr * 64 + ti * 16 + quad * 4 + i;
                    const size_t col = n0 + wc * 64 + tj * 16 + l15;
                    const float v = acc[ti][tj][i] + bv4[tj];
                    if constexpr (MODE == G_F32) {
                        ((float*)out0)[row * N + col] = v;
                    } else if constexpr (MODE == G_PV) {
                        ((bf16*)out0)[((size_t)z * 256 + row) * N + col] =
                            __float2bfloat16(v);
                    } else {  // G_SPLIT3: hi/lo outputs
                        const bf16 hb = __float2bfloat16(v);
                        ((bf16*)out0)[row * N + col] = hb;
                        ((bf16*)out1)[row * N + col] =
                            __float2bfloat16(v - __bfloat162float(hb));
                    }
                }
    }
}

// ---------------------------------------------------------------------------
// s + softmax + mask: block = (32 q-rows, batch); 512 thr = 8 waves
// wave = (wr 0..1 row-tile, wq 0..3 col-quarter). k hi/lo double-buffered in
// LDS (swizzled, conflict-free), counted-vmcnt 2-buffer schedule (S=4) +
// setprio around MFMA cluster (m191: +4-7% on role-diverse attn kernels).
// ---------------------------------------------------------------------------
__global__ __launch_bounds__(512) void attn_s(
    const bf16* __restrict__ qh, const bf16* __restrict__ ql,
    const bf16* __restrict__ kh, const bf16* __restrict__ kl,
    const float* __restrict__ masks, float* __restrict__ beta_out,
    bf16* __restrict__ betaB) {
    __shared__ bf16 kH[2][256 * 32], kL[2][256 * 32];
    __shared__ float redM[4][32], redS[4][32];
    int qt, b;
    swiz_xcd(qt, b);  // grid (8, 64): each XCD owns 8 batches; k fetched once
    const int tid = threadIdx.x, wave = tid >> 6, lane = tid & 63;
    const int quad = lane >> 4, l15 = lane & 15;
    const int wr = wave >> 2, wq = wave & 3;

    f32x4 acc[4] = {};
    const size_t qoff = ((size_t)(b * 256 + qt * 32 + wr * 16 + l15)) * 512;
    const size_t kbase = (size_t)(b * 256) * 512;

    stage_bf16_256_w8(kh + kbase, 512, kH[0], wave, lane);
    stage_bf16_256_w8(kl + kbase, 512, kL[0], wave, lane);
    stage_bf16_256_w8(kh + kbase + 32, 512, kH[1], wave, lane);
    stage_bf16_256_w8(kl + kbase + 32, 512, kL[1], wave, lane);
    int cur = 0;
    for (int t = 0; t < 16; ++t) {
        const int k0 = t * 32;
        if (t + 1 < 16)
            waitvm<4>();
        else
            waitvm<0>();
        __builtin_amdgcn_s_barrier();  // (A) tile t resident

        const short8 aH = *(const short8*)(qh + qoff + k0 + quad * 8);
        const short8 aL = *(const short8*)(ql + qoff + k0 + quad * 8);
        short8 bH[4], bL[4];
#pragma unroll
        for (int nt = 0; nt < 4; ++nt) {
            const int kr = wq * 64 + nt * 16 + l15;
            bH[nt] = rd_bf16(kH[cur], kr, quad);
            bL[nt] = rd_bf16(kL[cur], kr, quad);
        }
        lgkm0_fence();
        __builtin_amdgcn_s_barrier();  // (B) buf[cur] fully read
        if (t + 2 < 16) {
            stage_bf16_256_w8(kh + kbase + (t + 2) * 32, 512, kH[cur], wave, lane);
            stage_bf16_256_w8(kl + kbase + (t + 2) * 32, 512, kL[cur], wave, lane);
        }
        __builtin_amdgcn_s_setprio(1);
#pragma unroll
        for (int nt = 0; nt < 4; ++nt) {
            acc[nt] = MFMA_BF16(aH, bH[nt], acc[nt]);
            acc[nt] = MFMA_BF16(aH, bL[nt], acc[nt]);
            acc[nt] = MFMA_BF16(aL, bH[nt], acc[nt]);
        }
        __builtin_amdgcn_s_setprio(0);
        cur ^= 1;
    }

    // per-wave partial softmax over its 64 cols
    float pm[4], ps[4];
#pragma unroll
    for (int i = 0; i < 4; ++i) {
        float m = fmaxf(fmaxf(acc[0][i], acc[1][i]), fmaxf(acc[2][i], acc[3][i]));
#pragma unroll
        for (int s = 1; s < 16; s <<= 1) m = fmaxf(m, __shfl_xor(m, s));
        float sum = 0.f;
#pragma unroll
        for (int nt = 0; nt < 4; ++nt) sum += __expf(acc[nt][i] - m);
#pragma unroll
        for (int s = 1; s < 16; s <<= 1) sum += __shfl_xor(sum, s);
        pm[i] = m;
        ps[i] = sum;
    }
    if (l15 == 0) {
#pragma unroll
        for (int i = 0; i < 4; ++i) {
            redM[wq][wr * 16 + quad * 4 + i] = pm[i];
            redS[wq][wr * 16 + quad * 4 + i] = ps[i];
        }
    }
    __syncthreads();
    float gm[4], ginv[4];
#pragma unroll
    for (int i = 0; i < 4; ++i) {
        const int r = wr * 16 + quad * 4 + i;
        const float m = fmaxf(fmaxf(redM[0][r], redM[1][r]), fmaxf(redM[2][r], redM[3][r]));
        const float s = redS[0][r] * __expf(redM[0][r] - m) +
                        redS[1][r] * __expf(redM[1][r] - m) +
                        redS[2][r] * __expf(redM[2][r] - m) +
                        redS[3][r] * __expf(redM[3][r] - m);
        gm[i] = m;
        ginv[i] = 1.0f / s;
    }
#pragma unroll
    for (int nt = 0; nt < 4; ++nt) {
        const int col = wq * 64 + nt * 16 + l15;
        const float mv = masks[b * 256 + col];
#pragma unroll
        for (int i = 0; i < 4; ++i) {
            const int row = qt * 32 + wr * 16 + quad * 4 + i;
            const float bvv = __expf(acc[nt][i] - gm[i]) * ginv[i] * mv;
            const size_t idx = ((size_t)(b * 256 + row)) * 256 + col;
            beta_out[idx] = bvv;
            betaB[idx] = __float2bfloat16(bvv);
        }
    }
}

// ---------------------------------------------------------------------------
extern "C" void kernel_launch(void* const* d_in, const int* in_sizes, int n_in,
                              void* d_out, int out_size, void* d_ws, size_t ws_size,
                              hipStream_t stream) {
    const float* x1 = (const float*)d_in[0];
    const float* x2 = (const float*)d_in[1];
    const float* masks = (const float*)d_in[2];
    const float* Wq = (const float*)d_in[3];
    const float* bq = (const float*)d_in[4];
    const float* Wk = (const float*)d_in[5];
    const float* bk = (const float*)d_in[6];
    const float* Wv = (const float*)d_in[7];
    const float* bv = (const float*)d_in[8];
    const float* Wo = (const float*)d_in[9];
    const float* bo = (const float*)d_in[10];

    char* ws = (char*)d_ws;
    bf16* WqTh = (bf16*)(ws + 0);            // 512x1024
    bf16* WqTl = (bf16*)(ws + 1048576);
    bf16* WkTh = (bf16*)(ws + 2097152);      // 512x768
    bf16* WkTl = (bf16*)(ws + 2883584);
    bf16* WvTh = (bf16*)(ws + 3670016);      // 1024x768
    bf16* WoTh = (bf16*)(ws + 5242880);      // 1024x1024
    bf16* qh = (bf16*)(ws + 7340032);        // 16384x512
    bf16* ql = (bf16*)(ws + 24117248);
    bf16* kh = (bf16*)(ws + 40894464);
    bf16* kl = (bf16*)(ws + 57671680);
    bf16* vT = (bf16*)(ws + 74448896);       // [b][ch][tok] bf16
    bf16* betaB = (bf16*)(ws + 108003328);   // 16384x256
    bf16* o_mid = (bf16*)(ws + 7340032);     // overlays qh/ql (dead after attn_s)
    // total ws use: 116,391,936 bytes

    float* out_o = (float*)d_out;
    float* out_beta = out_o + (size_t)16384 * 1024;

    const dim3 tb(32, 8);
    transpose_split<true><<<dim3(16, 32), tb, 0, stream>>>(Wq, WqTh, WqTl, 1024, 512);
    transpose_split<true><<<dim3(16, 24), tb, 0, stream>>>(Wk, WkTh, WkTl, 768, 512);
    transpose_split<false><<<dim3(32, 24), tb, 0, stream>>>(Wv, WvTh, nullptr, 768, 1024);
    transpose_split<false><<<dim3(32, 32), tb, 0, stream>>>(Wo, WoTh, nullptr, 1024, 1024);

    // q = x1@Wq + bq -> hi/lo ; k = x2@Wk + bk -> hi/lo
    gemm2<G_SPLIT3><<<dim3(4, 128), 256, 0, stream>>>(x1, WqTh, WqTl, bq, qh, ql, 512, 1024);
    gemm2<G_SPLIT3><<<dim3(4, 128), 256, 0, stream>>>(x2, WkTh, WkTl, bk, kh, kl, 512, 768);
    // v = x2@Wv + bv -> vT[b][ch][tok]
    gemm2<G_VT><<<dim3(8, 128), 256, 0, stream>>>(x2, WvTh, nullptr, bv, vT, nullptr, 1024, 768);

    // s = q@k^T, softmax, mask -> beta (fp32 out + bf16 ws)
    attn_s<<<dim3(8, 64), 512, 0, stream>>>(qh, ql, kh, kl, masks, out_beta, betaB);

    // o_mid = beta @ v (batched)
    gemm2<G_PV><<<dim3(8, 2, 64), 256, 0, stream>>>(betaB, vT, nullptr, nullptr, o_mid,
                                                    nullptr, 1024, 256);
    // out = o_mid@Wo + bo (fp32)
    gemm2<G_F32><<<dim3(8, 128), 256, 0, stream>>>(o_mid, WoTh, nullptr, bo, out_o,
                                                   nullptr, 1024, 1024);
}

// Round 9
// 407.451 us; speedup vs baseline: 1.0483x; 1.0064x over previous
//
#include <hip/hip_runtime.h>
#include <hip/hip_bf16.h>

using bf16 = __hip_bfloat16;

typedef __attribute__((ext_vector_type(8))) short short8;   // 8 bf16 = 16B
typedef __attribute__((ext_vector_type(4))) float f32x4;    // 16B

#define MFMA_BF16(a, b, c) __builtin_amdgcn_mfma_f32_16x16x32_bf16((a), (b), (c), 0, 0, 0)

// async global->LDS, 16B per lane; LDS dest = wave-uniform base + lane*16
__device__ __forceinline__ void lds_load16(const void* g, void* l) {
    __builtin_amdgcn_global_load_lds(
        (const __attribute__((address_space(1))) void*)g,
        (__attribute__((address_space(3))) void*)l, 16, 0, 0);
}

// counted vmem wait (T4): wait until <= N vmem ops outstanding (oldest retire first)
template <int N>
__device__ __forceinline__ void waitvm() {
    asm volatile("s_waitcnt vmcnt(%0)" ::"n"(N) : "memory");
}
__device__ __forceinline__ void lgkm0_fence() {
    asm volatile("s_waitcnt lgkmcnt(0)" ::: "memory");
}

// XCD-aware block swizzle: flat%8 ~ XCD id. Requires gridDim.y % 8 == 0.
__device__ __forceinline__ void swiz_xcd(int& bx, int& by) {
    const int NX = gridDim.x, NY = gridDim.y;
    const int flat = blockIdx.y * NX + blockIdx.x;
    const int cid = flat & 7, slot = flat >> 3;
    by = cid * (NY >> 3) + slot / NX;
    bx = slot % NX;
}

// ---------------------------------------------------------------------------
// Bank-conflict-free staging (rule 21: LDS linear dest, XOR-permuted SOURCE,
// same XOR on the read side).
// ---------------------------------------------------------------------------
__device__ __forceinline__ void stage_bf16_128(const bf16* src, int ld, bf16* tile,
                                               int wave, int lane) {
    const int r = lane >> 2;                          // 16 rows / wave-issue
    const int c = ((lane & 3) ^ ((r >> 1) & 3)) * 8;  // swizzled source chunk
#pragma unroll
    for (int p = 0; p < 2; ++p) {
        const int row = p * 64 + wave * 16;           // base multiple of 16
        lds_load16(src + (size_t)(row + r) * ld + c, tile + row * 32);
    }
}
// 256x32 bf16 tile with 512-thr block (8 waves)
__device__ __forceinline__ void stage_bf16_256_w8(const bf16* src, int ld, bf16* tile,
                                                  int wave, int lane) {
    const int r = lane >> 2;
    const int c = ((lane & 3) ^ ((r >> 1) & 3)) * 8;
#pragma unroll
    for (int p = 0; p < 2; ++p) {
        const int row = p * 128 + wave * 16;
        lds_load16(src + (size_t)(row + r) * ld + c, tile + row * 32);
    }
}
// 128x32 fp32 tile, async (raw f32 into LDS; hi/lo conversion happens at read)
__device__ __forceinline__ void stage_f32_128(const float* src, int ld, float* tile,
                                              int wave, int lane) {
    const int r = lane >> 3;                          // 8 rows / wave-issue
    const int c = ((lane & 7) ^ r) * 4;               // swizzled source chunk
#pragma unroll
    for (int it = 0; it < 4; ++it) {
        const int row = it * 32 + wave * 8;           // base multiple of 8
        lds_load16(src + (size_t)(row + r) * ld + c, tile + row * 32);
    }
}

// swizzled reads ----------------------------------------------------------
__device__ __forceinline__ short8 rd_bf16(const bf16* tile, int row, int quad) {
    const int c = (quad ^ ((row >> 1) & 3)) * 8;
    return *(const short8*)(tile + row * 32 + c);
}
template <bool SPLIT>
__device__ __forceinline__ void rd_f32_hilo(const float* tile, int row, int quad,
                                            short8& h, short8& l) {
    const int f = row & 7;
    const f32x4 x0 = *(const f32x4*)(tile + row * 32 + ((2 * quad) ^ f) * 4);
    const f32x4 x1 = *(const f32x4*)(tile + row * 32 + ((2 * quad + 1) ^ f) * 4);
    float xs[8] = {x0[0], x0[1], x0[2], x0[3], x1[0], x1[1], x1[2], x1[3]};
#pragma unroll
    for (int j = 0; j < 8; ++j) {
        const bf16 hb = __float2bfloat16(xs[j]);
        h[j] = *(const short*)&hb;
        if constexpr (SPLIT) {
            const bf16 lb = __float2bfloat16(xs[j] - __bfloat162float(hb));
            l[j] = *(const short*)&lb;
        }
    }
}

// ---------------------------------------------------------------------------
// Weight transpose fp32 in[K][N] -> bf16 hi(/lo) out[N][K]
// ---------------------------------------------------------------------------
template <bool SPLIT>
__global__ void transpose_split(const float* __restrict__ in, bf16* __restrict__ outh,
                                bf16* __restrict__ outl, int K, int N) {
    __shared__ float t[32][33];
    const int n0 = blockIdx.x * 32, k0 = blockIdx.y * 32;
    const int tx = threadIdx.x, ty = threadIdx.y;  // (32, 8)
#pragma unroll
    for (int i = 0; i < 4; ++i)
        t[ty + i * 8][tx] = in[(size_t)(k0 + ty + i * 8) * N + n0 + tx];
    __syncthreads();
#pragma unroll
    for (int i = 0; i < 4; ++i) {
        const float x = t[tx][ty + i * 8];
        const bf16 hb = __float2bfloat16(x);
        const size_t idx = (size_t)(n0 + ty + i * 8) * K + k0 + tx;
        outh[idx] = hb;
        if constexpr (SPLIT) outl[idx] = __float2bfloat16(x - __bfloat162float(hb));
    }
}

// ---------------------------------------------------------------------------
// Unified 128x128x32 MFMA GEMM, C = A @ Bt^T (+bias). 256 thr = 4 waves.
// Wave decomposition (issue-slot optimized):
//  ACONV modes (fp32 A + in-reg hi/lo conv): 4x1 grid, wave owns 32x128 out
//    (acc[2][8]) -> A rows WAVE-EXCLUSIVE, so each fp32 element is converted
//    exactly once per block (2x2 duplicated conv across wave pairs was the
//    top VALU-issue consumer: ~120 of ~184 issues/wave/K-step).
//  non-ACONV (pure bf16): 2x2 grid, wave owns 64x64 (acc[4][4]) - minimal
//    LDS re-read amplification, no conv to dedupe.
// Per-mode best-measured K-loop schedule (R8 config):
//  SPLIT3: 2-phase dbuf, stage(t+1) BEFORE compute(t), one __syncthreads.
//  VT/F32/PV: counted-vmcnt 2-buffer: waitvm<S> -> barA -> ds_read -> lgkm0
//    -> barB -> stage(t+2) -> MFMA.
//  G_SPLIT3: A fp32 async, hi/lo conv in regs; B bf16 hi/lo; 3-MFMA.
//  G_VT    : A fp32 async, hi conv; B bf16; out bf16 transposed. S=6.
//  G_F32   : A bf16; B bf16; out fp32 + bias. S=4.
//  G_PV    : batched (z): A bf16; B bf16; out bf16, no bias. S=4.
// ---------------------------------------------------------------------------
enum { G_SPLIT3 = 0, G_VT = 1, G_F32 = 2, G_PV = 3 };

template <int MODE>
__global__ __launch_bounds__(256) void gemm2(
    const void* __restrict__ Av, const bf16* __restrict__ Bth,
    const bf16* __restrict__ Btl, const float* __restrict__ bias,
    void* __restrict__ out0, void* __restrict__ out1, int N, int K) {
    constexpr bool ASPLIT = (MODE == G_SPLIT3);
    constexpr bool ACONV = (MODE == G_SPLIT3 || MODE == G_VT);
    constexpr int TI = ACONV ? 2 : 4;       // 16-row tiles per wave
    constexpr int TJ = ACONV ? 8 : 4;       // 16-col tiles per wave
    constexpr int SZ_A = ACONV ? 128 * 32 * 4 : 128 * 32 * 2;
    constexpr int SZ_B = 128 * 32 * 2;
    constexpr int STAGE = SZ_A + SZ_B + (ASPLIT ? SZ_B : 0);
    constexpr int DBUF = 2 * STAGE;
    constexpr int SMEM =
        (MODE == G_VT) ? (DBUF > 128 * 136 * 2 ? DBUF : 128 * 136 * 2) : DBUF;
    constexpr int SLOADS = ACONV ? (ASPLIT ? 8 : 6) : 4;  // global_load_lds / lane / stage
    __shared__ __align__(16) char smem[SMEM];
    bf16* Ts = (bf16*)smem;  // G_VT epilogue only (staging dead by then)

    const int tid = threadIdx.x, wave = tid >> 6, lane = tid & 63;
    const int quad = lane >> 4, l15 = lane & 15;
    const int rbase = ACONV ? wave * 32 : (wave >> 1) * 64;  // wave row base
    const int cbase = ACONV ? 0 : (wave & 1) * 64;           // wave col base

    int bx, by;
    if constexpr (MODE == G_PV) {
        bx = blockIdx.x;
        by = blockIdx.y;
    } else {
        swiz_xcd(bx, by);
    }
    const int m0 = by * 128, n0 = bx * 128;
    const int z = blockIdx.z;

    const float* Af = (const float*)Av;
    const bf16* Ab = (const bf16*)Av;
    const bf16* Bh = Bth;
    if constexpr (MODE == G_PV) {
        Ab += (size_t)z * 256 * 256;   // beta batch
        Bh += (size_t)z * 1024 * 256;  // vT batch
    }

    auto do_stage = [&](int k0, char* base) {
        if constexpr (ACONV)
            stage_f32_128(Af + (size_t)m0 * K + k0, K, (float*)base, wave, lane);
        else
            stage_bf16_128(Ab + (size_t)m0 * K + k0, K, (bf16*)base, wave, lane);
        stage_bf16_128(Bh + (size_t)n0 * K + k0, K, (bf16*)(base + SZ_A), wave, lane);
        if constexpr (ASPLIT)
            stage_bf16_128(Btl + (size_t)n0 * K + k0, K, (bf16*)(base + SZ_A + SZ_B),
                           wave, lane);
    };

    f32x4 acc[TI][TJ] = {};

    auto compute = [&](char* base) {
        const float* AsF = (const float*)base;
        const bf16* AsH = (const bf16*)base;
        const bf16* BsH = (const bf16*)(base + SZ_A);
        const bf16* BsL = (const bf16*)(base + SZ_A + SZ_B);
        short8 ah[TI], al[TI];
#pragma unroll
        for (int ti = 0; ti < TI; ++ti) {
            const int ra = rbase + ti * 16 + l15;
            if constexpr (ACONV)
                rd_f32_hilo<ASPLIT>(AsF, ra, quad, ah[ti], al[ti]);
            else
                ah[ti] = rd_bf16(AsH, ra, quad);
        }
#pragma unroll
        for (int tj = 0; tj < TJ; ++tj) {
            const int rb = cbase + tj * 16 + l15;
            const short8 bh = rd_bf16(BsH, rb, quad);
            if constexpr (ASPLIT) {
                const short8 bl = rd_bf16(BsL, rb, quad);
#pragma unroll
                for (int ti = 0; ti < TI; ++ti) {
                    acc[ti][tj] = MFMA_BF16(al[ti], bh, acc[ti][tj]);
                    acc[ti][tj] = MFMA_BF16(ah[ti], bl, acc[ti][tj]);
                    acc[ti][tj] = MFMA_BF16(ah[ti], bh, acc[ti][tj]);
                }
            } else {
#pragma unroll
                for (int ti = 0; ti < TI; ++ti)
                    acc[ti][tj] = MFMA_BF16(ah[ti], bh, acc[ti][tj]);
            }
        }
    };

    const int nt = K / 32;
    int cur = 0;
    if constexpr (ASPLIT) {
        // R2-style 2-phase: stage(t+1) -> compute(t) -> one __syncthreads.
        do_stage(0, smem);
        __syncthreads();
        for (int t = 0; t < nt; ++t) {
            char* base = smem + cur * STAGE;
            if (t + 1 < nt) do_stage((t + 1) * 32, smem + (cur ^ 1) * STAGE);
            compute(base);
            __syncthreads();
            cur ^= 1;
        }
    } else {
        // R4-style counted-vmcnt 2-buffer (tile t+1 never drained).
        do_stage(0, smem);
        do_stage(32, smem + STAGE);
        for (int t = 0; t < nt; ++t) {
            if (t + 1 < nt)
                waitvm<SLOADS>();
            else
                waitvm<0>();
            __builtin_amdgcn_s_barrier();  // (A) tile t resident on all waves
            char* base = smem + cur * STAGE;
            compute(base);
            lgkm0_fence();
            __builtin_amdgcn_s_barrier();  // (B) buf[cur] fully read by all
            if (t + 2 < nt) do_stage((t + 2) * 32, base);
            cur ^= 1;
        }
    }

    float bv4[TJ];
#pragma unroll
    for (int tj = 0; tj < TJ; ++tj) bv4[tj] = 0.f;
    if constexpr (MODE != G_PV) {
#pragma unroll
        for (int tj = 0; tj < TJ; ++tj)
            bv4[tj] = bias[n0 + cbase + tj * 16 + l15];
    }

    if constexpr (MODE == G_VT) {
        __syncthreads();  // staging reads done before Ts overwrite
#pragma unroll
        for (int ti = 0; ti < TI; ++ti)
#pragma unroll
            for (int tj = 0; tj < TJ; ++tj)
#pragma unroll
                for (int i = 0; i < 4; ++i) {
                    const int ml = rbase + ti * 16 + quad * 4 + i;
                    const int nl = cbase + tj * 16 + l15;
                    Ts[nl * 136 + ml] = __float2bfloat16(acc[ti][tj][i] + bv4[tj]);
                }
        __syncthreads();
        const int bIdx = m0 >> 8, tok0 = m0 & 255;
        const int nl = tid >> 1, half = tid & 1;
        bf16* dst = (bf16*)out0 + ((size_t)bIdx * N + n0 + nl) * 256 + tok0 + half * 64;
        const bf16* src = &Ts[nl * 136 + half * 64];
#pragma unroll
        for (int j = 0; j < 8; ++j)
            *(short8*)(dst + j * 8) = *(const short8*)(src + j * 8);
    } else {
#pragma unroll
        for (int ti = 0; ti < TI; ++ti)
#pragma unroll
            for (int tj = 0; tj < TJ; ++tj)
#pragma unroll
                for (int i = 0; i < 4; ++i) {
                    const size_t row = m0 + rbase + ti * 16 + quad * 4 + i;
                    const size_t col = n0 + cbase + tj * 16 + l15;
                    const float v = acc[ti][tj][i] + bv4[tj];
                    if constexpr (MODE == G_F32) {
                        ((float*)out0)[row * N + col] = v;
                    } else if constexpr (MODE == G_PV) {
                        ((bf16*)out0)[((size_t)z * 256 + row) * N + col] =
                            __float2bfloat16(v);
                    } else {  // G_SPLIT3: hi/lo outputs
                        const bf16 hb = __float2bfloat16(v);
                        ((bf16*)out0)[row * N + col] = hb;
                        ((bf16*)out1)[row * N + col] =
                            __float2bfloat16(v - __bfloat162float(hb));
                    }
                }
    }
}

// ---------------------------------------------------------------------------
// s + softmax + mask: block = (32 q-rows, batch); 512 thr = 8 waves
// wave = (wr 0..1 row-tile, wq 0..3 col-quarter). k hi/lo double-buffered in
// LDS (swizzled, conflict-free), counted-vmcnt 2-buffer schedule (S=4) +
// setprio around MFMA cluster (m191: +4-7% on role-diverse attn kernels).
// ---------------------------------------------------------------------------
__global__ __launch_bounds__(512) void attn_s(
    const bf16* __restrict__ qh, const bf16* __restrict__ ql,
    const bf16* __restrict__ kh, const bf16* __restrict__ kl,
    const float* __restrict__ masks, float* __restrict__ beta_out,
    bf16* __restrict__ betaB) {
    __shared__ bf16 kH[2][256 * 32], kL[2][256 * 32];
    __shared__ float redM[4][32], redS[4][32];
    int qt, b;
    swiz_xcd(qt, b);  // grid (8, 64): each XCD owns 8 batches; k fetched once
    const int tid = threadIdx.x, wave = tid >> 6, lane = tid & 63;
    const int quad = lane >> 4, l15 = lane & 15;
    const int wr = wave >> 2, wq = wave & 3;

    f32x4 acc[4] = {};
    const size_t qoff = ((size_t)(b * 256 + qt * 32 + wr * 16 + l15)) * 512;
    const size_t kbase = (size_t)(b * 256) * 512;

    stage_bf16_256_w8(kh + kbase, 512, kH[0], wave, lane);
    stage_bf16_256_w8(kl + kbase, 512, kL[0], wave, lane);
    stage_bf16_256_w8(kh + kbase + 32, 512, kH[1], wave, lane);
    stage_bf16_256_w8(kl + kbase + 32, 512, kL[1], wave, lane);
    int cur = 0;
    for (int t = 0; t < 16; ++t) {
        const int k0 = t * 32;
        if (t + 1 < 16)
            waitvm<4>();
        else
            waitvm<0>();
        __builtin_amdgcn_s_barrier();  // (A) tile t resident

        const short8 aH = *(const short8*)(qh + qoff + k0 + quad * 8);
        const short8 aL = *(const short8*)(ql + qoff + k0 + quad * 8);
        short8 bH[4], bL[4];
#pragma unroll
        for (int nt = 0; nt < 4; ++nt) {
            const int kr = wq * 64 + nt * 16 + l15;
            bH[nt] = rd_bf16(kH[cur], kr, quad);
            bL[nt] = rd_bf16(kL[cur], kr, quad);
        }
        lgkm0_fence();
        __builtin_amdgcn_s_barrier();  // (B) buf[cur] fully read
        if (t + 2 < 16) {
            stage_bf16_256_w8(kh + kbase + (t + 2) * 32, 512, kH[cur], wave, lane);
            stage_bf16_256_w8(kl + kbase + (t + 2) * 32, 512, kL[cur], wave, lane);
        }
        __builtin_amdgcn_s_setprio(1);
#pragma unroll
        for (int nt = 0; nt < 4; ++nt) {
            acc[nt] = MFMA_BF16(aH, bH[nt], acc[nt]);
            acc[nt] = MFMA_BF16(aH, bL[nt], acc[nt]);
            acc[nt] = MFMA_BF16(aL, bH[nt], acc[nt]);
        }
        __builtin_amdgcn_s_setprio(0);
        cur ^= 1;
    }

    // per-wave partial softmax over its 64 cols
    float pm[4], ps[4];
#pragma unroll
    for (int i = 0; i < 4; ++i) {
        float m = fmaxf(fmaxf(acc[0][i], acc[1][i]), fmaxf(acc[2][i], acc[3][i]));
#pragma unroll
        for (int s = 1; s < 16; s <<= 1) m = fmaxf(m, __shfl_xor(m, s));
        float sum = 0.f;
#pragma unroll
        for (int nt = 0; nt < 4; ++nt) sum += __expf(acc[nt][i] - m);
#pragma unroll
        for (int s = 1; s < 16; s <<= 1) sum += __shfl_xor(sum, s);
        pm[i] = m;
        ps[i] = sum;
    }
    if (l15 == 0) {
#pragma unroll
        for (int i = 0; i < 4; ++i) {
            redM[wq][wr * 16 + quad * 4 + i] = pm[i];
            redS[wq][wr * 16 + quad * 4 + i] = ps[i];
        }
    }
    __syncthreads();
    float gm[4], ginv[4];
#pragma unroll
    for (int i = 0; i < 4; ++i) {
        const int r = wr * 16 + quad * 4 + i;
        const float m = fmaxf(fmaxf(redM[0][r], redM[1][r]), fmaxf(redM[2][r], redM[3][r]));
        const float s = redS[0][r] * __expf(redM[0][r] - m) +
                        redS[1][r] * __expf(redM[1][r] - m) +
                        redS[2][r] * __expf(redM[2][r] - m) +
                        redS[3][r] * __expf(redM[3][r] - m);
        gm[i] = m;
        ginv[i] = 1.0f / s;
    }
#pragma unroll
    for (int nt = 0; nt < 4; ++nt) {
        const int col = wq * 64 + nt * 16 + l15;
        const float mv = masks[b * 256 + col];
#pragma unroll
        for (int i = 0; i < 4; ++i) {
            const int row = qt * 32 + wr * 16 + quad * 4 + i;
            const float bvv = __expf(acc[nt][i] - gm[i]) * ginv[i] * mv;
            const size_t idx = ((size_t)(b * 256 + row)) * 256 + col;
            beta_out[idx] = bvv;
            betaB[idx] = __float2bfloat16(bvv);
        }
    }
}

// ---------------------------------------------------------------------------
extern "C" void kernel_launch(void* const* d_in, const int* in_sizes, int n_in,
                              void* d_out, int out_size, void* d_ws, size_t ws_size,
                              hipStream_t stream) {
    const float* x1 = (const float*)d_in[0];
    const float* x2 = (const float*)d_in[1];
    const float* masks = (const float*)d_in[2];
    const float* Wq = (const float*)d_in[3];
    const float* bq = (const float*)d_in[4];
    const float* Wk = (const float*)d_in[5];
    const float* bk = (const float*)d_in[6];
    const float* Wv = (const float*)d_in[7];
    const float* bv = (const float*)d_in[8];
    const float* Wo = (const float*)d_in[9];
    const float* bo = (const float*)d_in[10];

    char* ws = (char*)d_ws;
    bf16* WqTh = (bf16*)(ws + 0);            // 512x1024
    bf16* WqTl = (bf16*)(ws + 1048576);
    bf16* WkTh = (bf16*)(ws + 2097152);      // 512x768
    bf16* WkTl = (bf16*)(ws + 2883584);
    bf16* WvTh = (bf16*)(ws + 3670016);      // 1024x768
    bf16* WoTh = (bf16*)(ws + 5242880);      // 1024x1024
    bf16* qh = (bf16*)(ws + 7340032);        // 16384x512
    bf16* ql = (bf16*)(ws + 24117248);
    bf16* kh = (bf16*)(ws + 40894464);
    bf16* kl = (bf16*)(ws + 57671680);
    bf16* vT = (bf16*)(ws + 74448896);       // [b][ch][tok] bf16
    bf16* betaB = (bf16*)(ws + 108003328);   // 16384x256
    bf16* o_mid = (bf16*)(ws + 7340032);     // overlays qh/ql (dead after attn_s)
    // total ws use: 116,391,936 bytes

    float* out_o = (float*)d_out;
    float* out_beta = out_o + (size_t)16384 * 1024;

    const dim3 tb(32, 8);
    transpose_split<true><<<dim3(16, 32), tb, 0, stream>>>(Wq, WqTh, WqTl, 1024, 512);
    transpose_split<true><<<dim3(16, 24), tb, 0, stream>>>(Wk, WkTh, WkTl, 768, 512);
    transpose_split<false><<<dim3(32, 24), tb, 0, stream>>>(Wv, WvTh, nullptr, 768, 1024);
    transpose_split<false><<<dim3(32, 32), tb, 0, stream>>>(Wo, WoTh, nullptr, 1024, 1024);

    // q = x1@Wq + bq -> hi/lo ; k = x2@Wk + bk -> hi/lo
    gemm2<G_SPLIT3><<<dim3(4, 128), 256, 0, stream>>>(x1, WqTh, WqTl, bq, qh, ql, 512, 1024);
    gemm2<G_SPLIT3><<<dim3(4, 128), 256, 0, stream>>>(x2, WkTh, WkTl, bk, kh, kl, 512, 768);
    // v = x2@Wv + bv -> vT[b][ch][tok]
    gemm2<G_VT><<<dim3(8, 128), 256, 0, stream>>>(x2, WvTh, nullptr, bv, vT, nullptr, 1024, 768);

    // s = q@k^T, softmax, mask -> beta (fp32 out + bf16 ws)
    attn_s<<<dim3(8, 64), 512, 0, stream>>>(qh, ql, kh, kl, masks, out_beta, betaB);

    // o_mid = beta @ v (batched)
    gemm2<G_PV><<<dim3(8, 2, 64), 256, 0, stream>>>(betaB, vT, nullptr, nullptr, o_mid,
                                                    nullptr, 1024, 256);
    // out = o_mid@Wo + bo (fp32)
    gemm2<G_F32><<<dim3(8, 128), 256, 0, stream>>>(o_mid, WoTh, nullptr, bo, out_o,
                                                   nullptr, 1024, 1024);
}